// Round 1
// baseline (539.494 us; speedup 1.0000x reference)
//
#include <hip/hip_runtime.h>
#include <cstdint>

#define B_ 4
#define H_ 80
#define W_ 80
#define CH_ 256
#define NC_ 22
#define DIM_ 256
#define NPIX (B_*H_*W_)

// ---------------------------------------------------------------------------
// Phase 1: per-pixel sel[9] + norm, folded into ssel[k][m] = sel[k]*norm.
// sel[k] = sum over classes c where seg[center,c]==max_c(seg[center,:]) of
//          seg[neighbor_k, c]  (0 outside the image).
// cnt = #k with sel[k]!=0 ; norm = cnt>0 ? 9/cnt : 0.
// ---------------------------------------------------------------------------
__global__ __launch_bounds__(256) void sel_kernel(const float* __restrict__ seg,
                                                  float* __restrict__ ssel)
{
    int m = blockIdx.x * 256 + threadIdx.x;
    if (m >= NPIX) return;
    int w = m % W_;
    int h = (m / W_) % H_;
    int b = m / (W_ * H_);

    const float* c0 = seg + (size_t)m * NC_;
    float cv[NC_];
    float mx = -1e30f;
    #pragma unroll
    for (int c = 0; c < NC_; ++c) { cv[c] = c0[c]; mx = fmaxf(mx, cv[c]); }

    float sel[9];
    int cnt = 0;
    #pragma unroll
    for (int k = 0; k < 9; ++k) {
        int i = k / 3, j = k % 3;
        int hh = h + i - 1, ww = w + j - 1;
        float s = 0.f;
        if (hh >= 0 && hh < H_ && ww >= 0 && ww < W_) {
            const float* cn = seg + ((size_t)((b * H_ + hh) * W_ + ww)) * NC_;
            #pragma unroll
            for (int c = 0; c < NC_; ++c) {
                float v = cn[c];
                s += (cv[c] == mx) ? v : 0.f;
            }
        }
        sel[k] = s;
        cnt += (s != 0.f) ? 1 : 0;
    }
    float norm = (cnt > 0) ? 9.f / (float)cnt : 0.f;
    #pragma unroll
    for (int k = 0; k < 9; ++k)
        ssel[k * NPIX + m] = sel[k] * norm;
}

// ---------------------------------------------------------------------------
// Phase 2: implicit-GEMM 3x3 conv with per-(pixel,tap) scaling.
// Block: one image row (80 pixels) x 128 output dims. 256 threads:
//   tx = tid & 15  -> 8 consecutive d's each (d = d0 + tx*8 ..)
//   ty = tid >> 4  -> 5 consecutive pixels each (w = ty*5 ..)
// K-loop: 8 chunks of 32 channels; per chunk stage x (3 rows x 82 cols,
// c-major in LDS) once, then 9 taps each staging a 32x128 weight slab.
// ---------------------------------------------------------------------------
#define MT 80
#define NT 128
#define CC 32

__global__ __launch_bounds__(256) void conv_kernel(const float* __restrict__ x,
                                                   const float* __restrict__ cw,
                                                   const float* __restrict__ ssel,
                                                   float* __restrict__ out)
{
    __shared__ float xs[CC][3 * 82];   // [c][ri*82 + (w+1)]  c-major: conflict-free reads
    __shared__ float wl[CC][NT];       // [c][d]
    __shared__ float sl[9][MT];        // ssel staged for this row

    const int tid = threadIdx.x;
    const int tx = tid & 15;
    const int ty = tid >> 4;
    const int rt = blockIdx.x;         // 0..319  (b*H + h)
    const int b  = rt / H_;
    const int h  = rt % H_;
    const int d0 = blockIdx.y * NT;
    const int rowbase = rt * W_;       // global pixel index of w=0 in this row
    const int wbase = ty * 5;

    // stage ssel for the row (9 x 80)
    for (int t = tid; t < 9 * MT; t += 256) {
        int k = t / MT, wl_ = t % MT;
        sl[k][wl_] = ssel[k * NPIX + rowbase + wl_];
    }

    float acc[5][8];
    #pragma unroll
    for (int q = 0; q < 5; ++q)
        #pragma unroll
        for (int n = 0; n < 8; ++n) acc[q][n] = 0.f;

    for (int cc = 0; cc < CH_; cc += CC) {
        __syncthreads();   // previous iteration's reads of xs/wl are done
        // ---- stage x chunk: 3 rows x 82 cols (halo +-1) x 32 channels ----
        if (tid < 3 * 82) {
            const int ri = tid / 82;          // 0..2 -> image row h-1+ri
            const int wp = tid - ri * 82;     // 0..81 -> image col wp-1
            const int r  = h + ri - 1;
            const int ww = wp - 1;
            if (r >= 0 && r < H_ && ww >= 0 && ww < W_) {
                const float4* src =
                    (const float4*)(x + (((size_t)(b * H_ + r)) * W_ + ww) * CH_ + cc);
                #pragma unroll
                for (int f = 0; f < CC / 4; ++f) {
                    float4 v = src[f];
                    xs[4*f+0][tid] = v.x;
                    xs[4*f+1][tid] = v.y;
                    xs[4*f+2][tid] = v.z;
                    xs[4*f+3][tid] = v.w;
                }
            } else {
                #pragma unroll
                for (int f = 0; f < CC; ++f) xs[f][tid] = 0.f;
            }
        }

        for (int k = 0; k < 9; ++k) {
            __syncthreads();   // wl from previous tap fully consumed / xs staged
            // ---- stage weight slab for this tap: wl[c][d] = cw[(cc+c), k, d0+d] ----
            for (int t = tid; t < CC * (NT / 4); t += 256) {
                const int c  = t >> 5;        // NT/4 == 32
                const int d4 = t & 31;
                float4 v = *(const float4*)(cw + ((size_t)(cc + c) * 9 + k) * DIM_
                                               + d0 + d4 * 4);
                *(float4*)(&wl[c][d4 * 4]) = v;
            }
            __syncthreads();

            const int i = k / 3;
            const int j = k - 3 * i;
            float s[5];
            #pragma unroll
            for (int q = 0; q < 5; ++q) s[q] = sl[k][wbase + q];
            const int abase = i * 82 + wbase + j;   // xs col for pixel (wbase+q), tap (i,j)

            #pragma unroll 4
            for (int c = 0; c < CC; ++c) {
                float a[5];
                #pragma unroll
                for (int q = 0; q < 5; ++q) a[q] = xs[c][abase + q];
                const float4 b0 = *(const float4*)(&wl[c][tx * 8]);
                const float4 b1 = *(const float4*)(&wl[c][tx * 8 + 4]);
                #pragma unroll
                for (int q = 0; q < 5; ++q) {
                    const float t5 = s[q] * a[q];
                    acc[q][0] += t5 * b0.x;
                    acc[q][1] += t5 * b0.y;
                    acc[q][2] += t5 * b0.z;
                    acc[q][3] += t5 * b0.w;
                    acc[q][4] += t5 * b1.x;
                    acc[q][5] += t5 * b1.y;
                    acc[q][6] += t5 * b1.z;
                    acc[q][7] += t5 * b1.w;
                }
            }
        }
    }

    #pragma unroll
    for (int q = 0; q < 5; ++q) {
        float* dst = out + ((size_t)(rowbase + wbase + q)) * DIM_ + d0 + tx * 8;
        float4 o0 = make_float4(acc[q][0], acc[q][1], acc[q][2], acc[q][3]);
        float4 o1 = make_float4(acc[q][4], acc[q][5], acc[q][6], acc[q][7]);
        *(float4*)dst       = o0;
        *(float4*)(dst + 4) = o1;
    }
}

extern "C" void kernel_launch(void* const* d_in, const int* in_sizes, int n_in,
                              void* d_out, int out_size, void* d_ws, size_t ws_size,
                              hipStream_t stream)
{
    const float* x   = (const float*)d_in[0];   // (4,80,80,256) f32
    const float* seg = (const float*)d_in[1];   // (4,80,80,22)  f32
    const float* cw  = (const float*)d_in[2];   // (256,3,3,256) f32
    float* out  = (float*)d_out;                // (4,80,80,256) f32
    float* ssel = (float*)d_ws;                 // 9 * 25600 f32 scratch

    sel_kernel<<<dim3((NPIX + 255) / 256), dim3(256), 0, stream>>>(seg, ssel);
    conv_kernel<<<dim3(B_ * H_, DIM_ / NT), dim3(256), 0, stream>>>(x, cw, ssel, out);
}

// Round 2
// 173.574 us; speedup vs baseline: 3.1081x; 3.1081x over previous
//
#include <hip/hip_runtime.h>
#include <hip/hip_bf16.h>
#include <cstdint>

#define B_ 4
#define H_ 80
#define W_ 80
#define CH_ 256
#define NC_ 22
#define DIM_ 256
#define NPIX (B_*H_*W_)

typedef __attribute__((ext_vector_type(8))) short short8;     // 8 bf16 = 4 VGPR
typedef __attribute__((ext_vector_type(4))) float floatx4;    // MFMA C/D frag

static __device__ inline unsigned short f2bf(float v) {
    __hip_bfloat16 h = __float2bfloat16(v);   // RNE
    unsigned short r;
    __builtin_memcpy(&r, &h, 2);
    return r;
}

// ---------------------------------------------------------------------------
// Phase 1a: per-pixel ssel[k][m] = sel[k] * norm  (fp32, as round 1, float2 loads)
// ---------------------------------------------------------------------------
__global__ __launch_bounds__(256) void sel_kernel(const float* __restrict__ seg,
                                                  float* __restrict__ ssel)
{
    int m = blockIdx.x * 256 + threadIdx.x;
    if (m >= NPIX) return;
    int w = m % W_;
    int h = (m / W_) % H_;
    int b = m / (W_ * H_);

    const float2* c2 = (const float2*)(seg + (size_t)m * NC_);  // 8B aligned (22*4=88)
    float cv[NC_];
    #pragma unroll
    for (int c = 0; c < NC_ / 2; ++c) { float2 v = c2[c]; cv[2*c] = v.x; cv[2*c+1] = v.y; }
    float mx = -1e30f;
    #pragma unroll
    for (int c = 0; c < NC_; ++c) mx = fmaxf(mx, cv[c]);

    float sel[9];
    int cnt = 0;
    #pragma unroll
    for (int k = 0; k < 9; ++k) {
        int i = k / 3, j = k % 3;
        int hh = h + i - 1, ww = w + j - 1;
        float s = 0.f;
        if (hh >= 0 && hh < H_ && ww >= 0 && ww < W_) {
            const float2* n2 = (const float2*)(seg + ((size_t)((b * H_ + hh) * W_ + ww)) * NC_);
            #pragma unroll
            for (int c = 0; c < NC_ / 2; ++c) {
                float2 v = n2[c];
                s += (cv[2*c]   == mx) ? v.x : 0.f;
                s += (cv[2*c+1] == mx) ? v.y : 0.f;
            }
        }
        sel[k] = s;
        cnt += (s != 0.f) ? 1 : 0;
    }
    float norm = (cnt > 0) ? 9.f / (float)cnt : 0.f;
    #pragma unroll
    for (int k = 0; k < 9; ++k)
        ssel[k * NPIX + m] = sel[k] * norm;
}

// ---------------------------------------------------------------------------
// Phase 1b: weight repack+cast: cw[c][k][d] f32 -> wbT[k][d][c] bf16
// thread t -> (k, d, c8): 8 strided reads (L2-resident), one 16B packed write.
// ---------------------------------------------------------------------------
__global__ __launch_bounds__(256) void cvt_w_kernel(const float* __restrict__ cw,
                                                    unsigned short* __restrict__ wbT)
{
    int t = blockIdx.x * 256 + threadIdx.x;          // 9*256*32 = 73728 total
    if (t >= 9 * 256 * 32) return;
    int c8 = t & 31;
    int d  = (t >> 5) & 255;
    int k  = t >> 13;
    unsigned int u[4];
    #pragma unroll
    for (int e = 0; e < 4; ++e) {
        float v0 = cw[(size_t)(c8*8 + 2*e    ) * 9 * DIM_ + k * DIM_ + d];
        float v1 = cw[(size_t)(c8*8 + 2*e + 1) * 9 * DIM_ + k * DIM_ + d];
        u[e] = (unsigned)f2bf(v0) | ((unsigned)f2bf(v1) << 16);
    }
    uint4* dst = (uint4*)(wbT + ((size_t)k * 256 + d) * 256 + c8 * 8);
    *dst = make_uint4(u[0], u[1], u[2], u[3]);
}

// ---------------------------------------------------------------------------
// Phase 2: per-tap implicit GEMM, bf16 MFMA 16x16x32.
// Block: 1 image row (M=80 px) x 128 d. 4 waves, wave tile 80x32 (5x2 frags).
// Iter it in [0,72): tap k = it%9, c-chunk cc = (it/9)*32.
//   A-tile xsc[m][c] = bf16( x[b, h+i-1, m+j-1, cc+c] * ssel[k][m] )  (0 if OOB)
//   B-tile wl[d][c]  = wbT[k][d0+d][cc+c]
// Double-buffered LDS, 1 barrier/iter; global loads issued before MFMA,
// LDS writes after (software pipeline). Rows padded to 40 bf16 (80B = 20
// banks -> 2-way, free).
// ---------------------------------------------------------------------------
__global__ __launch_bounds__(256, 3) void conv_mfma(const float* __restrict__ x,
                                                    const float* __restrict__ ssel,
                                                    const unsigned short* __restrict__ wbT,
                                                    float* __restrict__ out)
{
    __shared__ __align__(16) unsigned short xsc[2][80][40];   // 12.5 KB
    __shared__ __align__(16) unsigned short wl[2][128][40];   // 20 KB
    __shared__ float sl[9][80];                               // 2.8 KB

    const int tid  = threadIdx.x;
    const int lane = tid & 63;
    const int wv   = tid >> 6;         // wave 0..3 -> d-offset wv*32
    const int ln   = lane & 15;
    const int quad = lane >> 4;
    const int rt   = blockIdx.x;       // b*H + h
    const int b    = rt / H_;
    const int h    = rt % H_;
    const int d0   = blockIdx.y * 128;

    // staging task mapping
    const bool xact = tid < 160;       // 80 rows x 2 halves
    const int  xtm  = tid >> 1;        // row m (pixel w within the row)
    const int  xth  = tid & 1;         // which 16-channel half
    const int  wtd  = tid >> 1;        // weight row d_local 0..127
    const int  wth  = tid & 1;         // which 16-channel half

    // stage ssel for this row
    for (int t = tid; t < 9 * 80; t += 256) {
        int k = t / 80, m = t - k * 80;
        sl[k][m] = ssel[k * NPIX + rt * W_ + m];
    }
    __syncthreads();

    floatx4 acc[5][2];
    #pragma unroll
    for (int i = 0; i < 5; ++i)
        #pragma unroll
        for (int j = 0; j < 2; ++j)
            acc[i][j] = (floatx4){0.f, 0.f, 0.f, 0.f};

    // pipeline registers
    float4 xr0, xr1, xr2, xr3;
    float4 wr0, wr1;
    float  sc = 0.f;
    bool   xnz = false;

    auto stage1 = [&](int it) {   // issue global loads for iteration `it`
        const int k2  = it % 9;
        const int cc2 = (it / 9) * 32;
        const int i2  = k2 / 3;
        const int j2  = k2 - 3 * i2;
        // weights: wbT[k2][d0+wtd][cc2 + wth*16 .. +15]
        const float4* q = (const float4*)(wbT + (((size_t)k2 * 256 + d0 + wtd) * 256
                                                 + cc2 + wth * 16));
        wr0 = q[0];
        wr1 = q[1];
        if (xact) {
            sc = sl[k2][xtm];
            const int r = h + i2 - 1;
            const int c = xtm + j2 - 1;
            xnz = (r >= 0) && (r < H_) && (c >= 0) && (c < W_);
            if (xnz) {
                const float4* p = (const float4*)(x + ((((size_t)b * H_ + r) * W_ + c) * CH_
                                                       + cc2 + xth * 16));
                xr0 = p[0]; xr1 = p[1]; xr2 = p[2]; xr3 = p[3];
            }
        }
    };

    auto stage2 = [&](int it) {   // scale/pack + LDS writes for iteration `it`
        const int buf = it & 1;
        float4* wd = (float4*)&wl[buf][wtd][wth * 16];
        wd[0] = wr0;
        wd[1] = wr1;
        if (xact) {
            unsigned int u[8];
            if (xnz) {
                float f[16] = {xr0.x, xr0.y, xr0.z, xr0.w, xr1.x, xr1.y, xr1.z, xr1.w,
                               xr2.x, xr2.y, xr2.z, xr2.w, xr3.x, xr3.y, xr3.z, xr3.w};
                #pragma unroll
                for (int e = 0; e < 8; ++e)
                    u[e] = (unsigned)f2bf(f[2*e] * sc) | ((unsigned)f2bf(f[2*e+1] * sc) << 16);
            } else {
                #pragma unroll
                for (int e = 0; e < 8; ++e) u[e] = 0u;
            }
            uint4* xd = (uint4*)&xsc[buf][xtm][xth * 16];
            xd[0] = make_uint4(u[0], u[1], u[2], u[3]);
            xd[1] = make_uint4(u[4], u[5], u[6], u[7]);
        }
    };

    // prologue: stage iteration 0 into buf 0
    stage1(0);
    stage2(0);
    __syncthreads();

    for (int it = 0; it < 72; ++it) {
        const int nit = it + 1;
        if (nit < 72) stage1(nit);        // globals in flight during MFMA

        const int buf = it & 1;
        short8 a[5];
        #pragma unroll
        for (int i = 0; i < 5; ++i)
            a[i] = *(const short8*)&xsc[buf][i * 16 + ln][quad * 8];
        short8 bb[2];
        #pragma unroll
        for (int j = 0; j < 2; ++j)
            bb[j] = *(const short8*)&wl[buf][wv * 32 + j * 16 + ln][quad * 8];
        #pragma unroll
        for (int i = 0; i < 5; ++i)
            #pragma unroll
            for (int j = 0; j < 2; ++j)
                acc[i][j] = __builtin_amdgcn_mfma_f32_16x16x32_bf16(a[i], bb[j], acc[i][j],
                                                                    0, 0, 0);

        if (nit < 72) stage2(nit);        // vmcnt wait lands here, not before MFMA
        __syncthreads();
    }

    // epilogue: C/D layout col(d)=lane&15, row(m)=quad*4+reg  [m89/m91]
    #pragma unroll
    for (int i = 0; i < 5; ++i) {
        #pragma unroll
        for (int j = 0; j < 2; ++j) {
            const int dd = d0 + wv * 32 + j * 16 + ln;
            #pragma unroll
            for (int r = 0; r < 4; ++r) {
                const int m = i * 16 + quad * 4 + r;
                out[((size_t)(rt * W_ + m)) * DIM_ + dd] = acc[i][j][r];
            }
        }
    }
}

extern "C" void kernel_launch(void* const* d_in, const int* in_sizes, int n_in,
                              void* d_out, int out_size, void* d_ws, size_t ws_size,
                              hipStream_t stream)
{
    const float* x   = (const float*)d_in[0];   // (4,80,80,256) f32
    const float* seg = (const float*)d_in[1];   // (4,80,80,22)  f32
    const float* cw  = (const float*)d_in[2];   // (256,3,3,256) f32
    float* out = (float*)d_out;                 // (4,80,80,256) f32

    float*          ssel = (float*)d_ws;                         // 9*25600*4 = 921600 B
    unsigned short* wbT  = (unsigned short*)((char*)d_ws + 921600); // 9*256*256*2 = 1179648 B

    sel_kernel<<<dim3((NPIX + 255) / 256), dim3(256), 0, stream>>>(seg, ssel);
    cvt_w_kernel<<<dim3(288), dim3(256), 0, stream>>>(cw, wbT);
    conv_mfma<<<dim3(B_ * H_, DIM_ / 128), dim3(256), 0, stream>>>(x, ssel, wbT, out);
}

// Round 3
// 158.174 us; speedup vs baseline: 3.4108x; 1.0974x over previous
//
#include <hip/hip_runtime.h>
#include <hip/hip_bf16.h>
#include <cstdint>

#define B_ 4
#define H_ 80
#define W_ 80
#define CH_ 256
#define NC_ 22
#define DIM_ 256
#define NPIX (B_*H_*W_)

typedef unsigned short ushort;
typedef __attribute__((ext_vector_type(8))) short short8;     // 8 bf16 = 4 VGPR
typedef __attribute__((ext_vector_type(4))) float floatx4;    // MFMA C/D frag

static __device__ inline ushort f2bf(float v) {
    __hip_bfloat16 h = __float2bfloat16(v);   // RNE
    ushort r;
    __builtin_memcpy(&r, &h, 2);
    return r;
}
static __device__ inline unsigned pk2(float a, float b) {
    return (unsigned)f2bf(a) | ((unsigned)f2bf(b) << 16);
}

// ---------------------------------------------------------------------------
// Phase 1a: ssel[k][m] = sel[k]*norm (fp32). 64-thread blocks -> 400 blocks.
// ---------------------------------------------------------------------------
__global__ __launch_bounds__(64) void sel_kernel(const float* __restrict__ seg,
                                                 float* __restrict__ ssel)
{
    int m = blockIdx.x * 64 + threadIdx.x;
    if (m >= NPIX) return;
    int w = m % W_;
    int h = (m / W_) % H_;
    int b = m / (W_ * H_);

    const float2* c2 = (const float2*)(seg + (size_t)m * NC_);
    float cv[NC_];
    #pragma unroll
    for (int c = 0; c < NC_ / 2; ++c) { float2 v = c2[c]; cv[2*c] = v.x; cv[2*c+1] = v.y; }
    float mx = -1e30f;
    #pragma unroll
    for (int c = 0; c < NC_; ++c) mx = fmaxf(mx, cv[c]);

    float sel[9];
    int cnt = 0;
    #pragma unroll
    for (int k = 0; k < 9; ++k) {
        int i = k / 3, j = k % 3;
        int hh = h + i - 1, ww = w + j - 1;
        float s = 0.f;
        if (hh >= 0 && hh < H_ && ww >= 0 && ww < W_) {
            const float2* n2 = (const float2*)(seg + ((size_t)((b * H_ + hh) * W_ + ww)) * NC_);
            #pragma unroll
            for (int c = 0; c < NC_ / 2; ++c) {
                float2 v = n2[c];
                s += (cv[2*c]   == mx) ? v.x : 0.f;
                s += (cv[2*c+1] == mx) ? v.y : 0.f;
            }
        }
        sel[k] = s;
        cnt += (s != 0.f) ? 1 : 0;
    }
    float norm = (cnt > 0) ? 9.f / (float)cnt : 0.f;
    #pragma unroll
    for (int k = 0; k < 9; ++k)
        ssel[k * NPIX + m] = sel[k] * norm;
}

// ---------------------------------------------------------------------------
// Phase 1b: weight repack via LDS transpose: cw[c][k][d] f32 -> wbT[k][d][c] bf16.
// Block = (k, 32-c chunk): coalesced 1KB row reads, LDS transpose, 64B writes.
// ---------------------------------------------------------------------------
__global__ __launch_bounds__(256) void cvt_w(const float* __restrict__ cw,
                                             ushort* __restrict__ wbT)
{
    __shared__ ushort ls[32][260];           // pad 4 -> 2-way max on reads
    const int k  = blockIdx.x / 8;
    const int c0 = (blockIdx.x % 8) * 32;
    const int c   = threadIdx.x >> 3;        // 0..31
    const int seg = threadIdx.x & 7;         // 0..7  (32 d's each)

    const float* src = cw + ((size_t)(c0 + c) * 9 + k) * DIM_ + seg * 32;
    #pragma unroll
    for (int e = 0; e < 32; e += 4) {
        float4 v = *(const float4*)(src + e);
        unsigned* dst = (unsigned*)&ls[c][seg * 32 + e];
        dst[0] = pk2(v.x, v.y);
        dst[1] = pk2(v.z, v.w);
    }
    __syncthreads();

    const int d = threadIdx.x;               // 0..255
    ushort tmp[32];
    #pragma unroll
    for (int cc = 0; cc < 32; ++cc) tmp[cc] = ls[cc][d];
    uint4 o[4];
    __builtin_memcpy(o, tmp, 64);
    uint4* dst = (uint4*)(wbT + ((size_t)k * 256 + d) * 256 + c0);
    dst[0] = o[0]; dst[1] = o[1]; dst[2] = o[2]; dst[3] = o[3];
}

// ---------------------------------------------------------------------------
// Phase 1c: x f32 -> xb bf16 (13 MB). 8 elems/thread.
// ---------------------------------------------------------------------------
__global__ __launch_bounds__(256) void cvt_x(const float* __restrict__ x,
                                             ushort* __restrict__ xb)
{
    size_t idx = ((size_t)blockIdx.x * 256 + threadIdx.x) * 8;
    const float4* s = (const float4*)(x + idx);
    float4 a = s[0], b = s[1];
    uint4 o = make_uint4(pk2(a.x, a.y), pk2(a.z, a.w), pk2(b.x, b.y), pk2(b.z, b.w));
    *(uint4*)(xb + idx) = o;
}

// ---------------------------------------------------------------------------
// Phase 2: taps-outer implicit GEMM. Block = row (M=80) x 128 d, 4 waves.
// Interval it in [0,18): i = it/6, cc = ((it%6)/3)*128, j = it%3, tap k=3i+j.
// Per interval: P (fresh accum) += A_chunk * B_chunk over 4 kk-steps of 32;
// then O += ssel_k[m] * P  (scale in fp32 on the C-fragment).
// A: LDS double-buffered, rows padded to 136 ush (272 B). B: global->reg,
// prefetched one interval ahead (short8 Breg[8]). One barrier per interval.
// ---------------------------------------------------------------------------
template<bool XB16>
__global__ __launch_bounds__(256, 3) void conv2(const float* __restrict__ x,
                                                const ushort* __restrict__ xb,
                                                const float* __restrict__ ssel,
                                                const ushort* __restrict__ wbT,
                                                float* __restrict__ out)
{
    __shared__ ushort xsA[2][80 * 136];      // 43.5 KB
    __shared__ float  sl[9][80];             // 2.8 KB

    const int tid  = threadIdx.x;
    const int lane = tid & 63;
    const int wv   = tid >> 6;               // d-offset wv*32
    const int ln   = lane & 15;
    const int quad = lane >> 4;
    const int rt   = blockIdx.x;             // b*H + h
    const int b    = rt / H_;
    const int h    = rt % H_;
    const int d0   = blockIdx.y * 128;

    // per-thread staging chunk constants: q = tid + 256*r -> (pixel m, 16B block cb)
    int qm[5], qc[5];
    #pragma unroll
    for (int r = 0; r < 5; ++r) {
        int q = tid + 256 * r;
        qm[r] = q >> 4;
        qc[r] = q & 15;
    }

    // stage ssel row
    for (int t = tid; t < 9 * 80; t += 256) {
        int k = t / 80, m = t - k * 80;
        sl[k][m] = ssel[k * NPIX + rt * W_ + m];
    }

    floatx4 O[5][2];
    #pragma unroll
    for (int i = 0; i < 5; ++i)
        #pragma unroll
        for (int jn = 0; jn < 2; ++jn)
            O[i][jn] = (floatx4){0.f, 0.f, 0.f, 0.f};

    // staging pipeline registers
    uint4  sg[5];                    // bf16 path
    float4 fa[5], fb[5];             // fp32 path
    bool   ok[5];

    auto stage_load = [&](int nit) {
        const int i   = nit / 6;
        const int rem = nit % 6;
        const int cc  = (rem / 3) * 128;
        const int jj  = rem % 3;
        const int rr  = h + i - 1;
        const bool rowok = (rr >= 0) && (rr < H_);
        const int rsafe = rowok ? rr : h;
        #pragma unroll
        for (int r = 0; r < 5; ++r) {
            const int col = qm[r] + jj - 1;
            const bool v = rowok && (col >= 0) && (col < W_);
            ok[r] = v;
            const size_t gp = ((size_t)(b * H_ + rsafe) * W_ + (v ? col : 0));
            if (XB16) {
                sg[r] = *(const uint4*)(xb + gp * CH_ + cc + qc[r] * 8);
            } else {
                const float* f = x + gp * CH_ + cc + qc[r] * 8;
                fa[r] = *(const float4*)f;
                fb[r] = *(const float4*)(f + 4);
            }
        }
    };
    auto stage_write = [&](int nit) {
        ushort* bp = xsA[nit & 1];
        #pragma unroll
        for (int r = 0; r < 5; ++r) {
            uint4 v;
            if (XB16) {
                v = ok[r] ? sg[r] : make_uint4(0u, 0u, 0u, 0u);
            } else {
                v = ok[r] ? make_uint4(pk2(fa[r].x, fa[r].y), pk2(fa[r].z, fa[r].w),
                                       pk2(fb[r].x, fb[r].y), pk2(fb[r].z, fb[r].w))
                          : make_uint4(0u, 0u, 0u, 0u);
            }
            *(uint4*)&bp[qm[r] * 136 + qc[r] * 8] = v;
        }
    };

    short8 Breg[8];                  // [kk][jn] for current interval
    auto loadB = [&](int nit) {
        const int i   = nit / 6;
        const int rem = nit % 6;
        const int cc  = (rem / 3) * 128;
        const int jj  = rem % 3;
        const int k   = 3 * i + jj;
        #pragma unroll
        for (int kk = 0; kk < 4; ++kk)
            #pragma unroll
            for (int jn = 0; jn < 2; ++jn)
                Breg[kk * 2 + jn] = *(const short8*)(wbT
                    + ((size_t)k * 256 + d0 + wv * 32 + jn * 16 + ln) * 256
                    + cc + kk * 32 + quad * 8);
    };

    // prologue
    stage_load(0);
    stage_write(0);
    loadB(0);
    __syncthreads();

    #pragma unroll 2
    for (int it = 0; it < 18; ++it) {
        const int i   = it / 6;
        const int rem = it % 6;
        const int jj  = rem % 3;
        const int k   = 3 * i + jj;
        const ushort* bp = xsA[it & 1];

        if (it < 17) stage_load(it + 1);     // globals in flight during MFMA

        floatx4 P[5][2];
        #pragma unroll
        for (int im = 0; im < 5; ++im)
            #pragma unroll
            for (int jn = 0; jn < 2; ++jn)
                P[im][jn] = (floatx4){0.f, 0.f, 0.f, 0.f};

        #pragma unroll
        for (int kk = 0; kk < 4; ++kk) {
            short8 a[5];
            #pragma unroll
            for (int im = 0; im < 5; ++im)
                a[im] = *(const short8*)&bp[(im * 16 + ln) * 136 + kk * 32 + quad * 8];
            #pragma unroll
            for (int im = 0; im < 5; ++im)
                #pragma unroll
                for (int jn = 0; jn < 2; ++jn)
                    P[im][jn] = __builtin_amdgcn_mfma_f32_16x16x32_bf16(
                        a[im], Breg[kk * 2 + jn], P[im][jn], 0, 0, 0);
        }

        if (it < 17) stage_write(it + 1);    // vmcnt wait lands after MFMA
        if (it < 17) loadB(it + 1);          // B for next interval in flight

        // scale-accumulate: O += s_k[m] * P  (row m = i*16 + quad*4 + r)
        #pragma unroll
        for (int im = 0; im < 5; ++im) {
            const float4 sv = *(const float4*)&sl[k][im * 16 + quad * 4];
            #pragma unroll
            for (int jn = 0; jn < 2; ++jn) {
                O[im][jn][0] += sv.x * P[im][jn][0];
                O[im][jn][1] += sv.y * P[im][jn][1];
                O[im][jn][2] += sv.z * P[im][jn][2];
                O[im][jn][3] += sv.w * P[im][jn][3];
            }
        }
        __syncthreads();
    }

    // epilogue: C/D layout col(d)=lane&15, row(m)=quad*4+reg
    #pragma unroll
    for (int im = 0; im < 5; ++im) {
        #pragma unroll
        for (int jn = 0; jn < 2; ++jn) {
            const int dd = d0 + wv * 32 + jn * 16 + ln;
            #pragma unroll
            for (int r = 0; r < 4; ++r) {
                const int m = im * 16 + quad * 4 + r;
                out[((size_t)(rt * W_ + m)) * DIM_ + dd] = O[im][jn][r];
            }
        }
    }
}

extern "C" void kernel_launch(void* const* d_in, const int* in_sizes, int n_in,
                              void* d_out, int out_size, void* d_ws, size_t ws_size,
                              hipStream_t stream)
{
    const float* x   = (const float*)d_in[0];   // (4,80,80,256) f32
    const float* seg = (const float*)d_in[1];   // (4,80,80,22)  f32
    const float* cw  = (const float*)d_in[2];   // (256,3,3,256) f32
    float* out = (float*)d_out;

    float*  ssel = (float*)d_ws;                                   // 921600 B
    ushort* wbT  = (ushort*)((char*)d_ws + 921600);                // 1179648 B
    ushort* xb   = (ushort*)((char*)d_ws + 921600 + 1179648);      // 13107200 B
    const size_t need = 921600u + 1179648u + 13107200u;

    sel_kernel<<<dim3((NPIX + 63) / 64), dim3(64), 0, stream>>>(seg, ssel);
    cvt_w<<<dim3(72), dim3(256), 0, stream>>>(cw, wbT);

    if (ws_size >= need) {
        cvt_x<<<dim3(NPIX * CH_ / (256 * 8)), dim3(256), 0, stream>>>(x, xb);
        conv2<true><<<dim3(B_ * H_, 2), dim3(256), 0, stream>>>(x, xb, ssel, wbT, out);
    } else {
        conv2<false><<<dim3(B_ * H_, 2), dim3(256), 0, stream>>>(x, nullptr, ssel, wbT, out);
    }
}